// Round 2
// baseline (153.673 us; speedup 1.0000x reference)
//
#include <hip/hip_runtime.h>
#include <math.h>

#define NB 65
#define HOPS 256
#define RPB 8           // rows per block
#define THREADS 128     // 16 lanes per row; 2 waves/block, each wave owns 4 rows
#define TAPS_OFF 360    // phys size of swizzled 320-float pad region (320 + 10*4 pad)
#define RSTRIDE 492     // 360 pad(phys) + 128 taps + 4 (492%32==12 rotates rows)

// Swizzle: +4 floats of pad every 32 floats (logical pad region [0,320)).
// Logical layout per row: [0,64) zeros, [64,320) noise (2u-1); taps at [TAPS_OFF,+128).
#define PHYS(i) ((i) + (((i) >> 5) << 2))

// Zero-cost phase fence: all LDS traffic is intra-wave (DS pipe is in-order per
// wave), so we only need to stop the COMPILER from moving memory ops across.
#define WAVE_FENCE() do { asm volatile("" ::: "memory"); __builtin_amdgcn_wave_barrier(); } while (0)

__device__ __forceinline__ void load16(float (&d)[16], const float* p) {
#pragma unroll
    for (int x = 0; x < 4; ++x) {
        float4 v = *(const float4*)(p + 4 * x);
        d[4*x] = v.x; d[4*x+1] = v.y; d[4*x+2] = v.z; d[4*x+3] = v.w;
    }
}
__device__ __forceinline__ void load16s(float (&d)[16], const float* rowbuf, int L) {
#pragma unroll
    for (int x = 0; x < 4; ++x) {
        float4 v = *(const float4*)(rowbuf + PHYS(L + 4 * x));
        d[4*x] = v.x; d[4*x+1] = v.y; d[4*x+2] = v.z; d[4*x+3] = v.w;
    }
}
// window w[j] = j<16 ? lo[j] : hi[j-16], j = 16+d-kk in [1,31]
__device__ __forceinline__ void fma16(float (&f)[16], const float (&tp)[16],
                                      const float (&lo)[16], const float (&hi)[16]) {
#pragma unroll
    for (int kk = 0; kk < 16; ++kk) {
        float t = tp[kk];
#pragma unroll
        for (int d = 0; d < 16; ++d) {
            int j = 16 + d - kk;
            f[d] = fmaf(t, (j < 16) ? lo[j] : hi[j - 16], f[d]);
        }
    }
}

__global__ __launch_bounds__(THREADS, 4) void noisefilter_kernel(
    const float* __restrict__ fb,   // [65536][65]
    const float* __restrict__ nz,   // [65536][256]
    float* __restrict__ out)        // [65536][256]
{
    __shared__ float lds[RPB * RSTRIDE];
    const int tid  = threadIdx.x;
    const int wv   = tid >> 6;       // wave within block (0,1); wave owns rows 4wv..4wv+3
    const int lane = tid & 63;
    const int r    = tid >> 4;       // row within block (0..7)
    const int l16  = tid & 15;       // lane within row group
    const int t0   = l16 << 4;       // first output index of this thread
    const size_t row0 = (size_t)blockIdx.x * RPB;
    float* rowbuf = &lds[r * RSTRIDE];

    // ---- stage amp (65 floats/row) — each wave stages ITS OWN 4 rows ----
    {
        const float* fbw = fb + (row0 + 4 * wv) * NB;
        float* base = &lds[(4 * wv) * RSTRIDE];
        for (int i = lane; i < 4 * NB; i += 64) {
            int rr = i / NB;
            int k  = i - rr * NB;
            base[rr * RSTRIDE + TAPS_OFF + k] = fbw[i];
        }
    }

    // ---- prefetch noise for own wave's 4 rows (consumed after Goertzel) ----
    const float4* nz4 = (const float4*)(nz + (row0 + 4 * wv) * HOPS);
    float4 nv[4];
#pragma unroll
    for (int p = 0; p < 4; ++p) nv[p] = nz4[lane + p * 64];

    WAVE_FENCE();   // amp ds_writes above, Goertzel ds_reads below (intra-wave, in-order)

    // ---- Phase A: even/odd-split Goertzel; lane gets (nA,64-nA),(nB,64-nB), n=32 shared.
    const float alphaA = (float)l16 * 0.04908738521234052f;          // pi/64 * nA
    const float alphaB = alphaA + 0.7853981633974483f;               // + pi/4
    const float cA = __cosf(alphaA), cB = __cosf(alphaB);
    const float c2A = fmaf(2.0f * cA, cA, -1.0f);                    // cos(2a)
    const float c2B = fmaf(2.0f * cB, cB, -1.0f);
    const float k2A = c2A + c2A, k2B = c2B + c2B;

    float eA1=0.f,eA2=0.f,oA1=0.f,oA2=0.f;
    float eB1=0.f,eB2=0.f,oB1=0.f,oB2=0.f;
    float s32 = 0.f, a0r = 0.f, a64r;

    const float* amp = rowbuf + TAPS_OFF;
    {   // k = 64 (even chain m=32; n=32 sign +)
        float a = amp[64];
        a64r = a;
        { float t = a - eA2; float s = fmaf(k2A, eA1, t); eA2 = eA1; eA1 = s; }
        { float t = a - eB2; float s = fmaf(k2B, eB1, t); eB2 = eB1; eB1 = s; }
        s32 += a;
    }
#pragma unroll
    for (int kb = 48; kb >= 0; kb -= 16) {
        float ab[16];
        load16(ab, amp + kb);
#pragma unroll
        for (int kk = 15; kk >= 0; --kk) {
            float a = ab[kk];
            if (kk & 1) {   // odd k
                { float t = a - oA2; float s = fmaf(k2A, oA1, t); oA2 = oA1; oA1 = s; }
                { float t = a - oB2; float s = fmaf(k2B, oB1, t); oB2 = oB1; oB1 = s; }
            } else {        // even k
                { float t = a - eA2; float s = fmaf(k2A, eA1, t); eA2 = eA1; eA1 = s; }
                { float t = a - eB2; float s = fmaf(k2B, eB1, t); eB2 = eB1; eB1 = s; }
                if ((kk >> 1) & 1) s32 -= a; else s32 += a;
            }
        }
        if (kb == 0) a0r = ab[0];
    }

    const float EA = fmaf(-c2A, eA2, eA1);
    const float OA = cA * (oA1 - oA2);
    const float EB = fmaf(-c2B, eB2, eB1);
    const float OB = cB * (oB1 - oB2);
    const float pm = (l16 & 1) ? -1.f : 1.f;      // (-1)^n
    const float corr = fmaf(pm, a64r, a0r);
    const float inv = 1.0f / 256.0f;
    float* tps = rowbuf + TAPS_OFF;

    {   // pair A: n = l16, mirror 64-l16
        float GA  = fmaf(2.f, EA + OA, -corr);
        float GAm = fmaf(2.f, EA - OA, -corr);
        float TA  = GA  * (1.0f + cA) * inv;
        float TAm = GAm * (1.0f - cA) * inv;
        tps[l16] = TA;
        tps[64 - l16] = TAm;
        if (l16 >= 1) { tps[128 - l16] = TA; tps[64 + l16] = TAm; }
    }
    {   // pair B: n = 16+l16, mirror 48-l16
        float GB  = fmaf(2.f, EB + OB, -corr);
        float GBm = fmaf(2.f, EB - OB, -corr);
        float TB  = GB  * (1.0f + cB) * inv;
        float TBm = GBm * (1.0f - cB) * inv;
        tps[16 + l16] = TB;  tps[112 - l16] = TB;
        tps[48 - l16] = TBm; tps[80 + l16]  = TBm;
    }
    if (l16 == 0) {   // n = 32 (single lane: avoid 16-way same-address write)
        float G32 = fmaf(2.f, s32, -(a0r + a64r));
        float T32 = G32 * inv;
        tps[32] = T32;
        tps[96] = T32;
    }

    // ---- zero logical [0,64) of own row (one float4 per lane) ----
    *(float4*)(rowbuf + PHYS(4 * l16)) = make_float4(0.f, 0.f, 0.f, 0.f);

    // ---- store noise (2u-1) into logical [64,320) of own wave's rows ----
#pragma unroll
    for (int p = 0; p < 4; ++p) {
        float4 v = nv[p];
        int o  = (lane << 2) + 64;          // idx = lane + 64p -> row 4wv+p, offset 4*lane+64
        *(float4*)(&lds[(4 * wv + p) * RSTRIDE + PHYS(o)]) =
            make_float4(fmaf(2.f, v.x, -1.f), fmaf(2.f, v.y, -1.f),
                        fmaf(2.f, v.z, -1.f), fmaf(2.f, v.w, -1.f));
    }

    WAVE_FENCE();   // tap/zero/noise ds_writes above, C1/C2 ds_reads below (intra-wave)

    // ---- Phase C1: taps 0..63 (delays 0..63), all 256 outputs, sliding window ----
    float f[16];
#pragma unroll
    for (int d = 0; d < 16; ++d) f[d] = 0.f;
    float X[16], Y[16], Z[16], tp[16];
    {
        const int b0 = t0 + 48;
        load16s(X, rowbuf, b0);      load16s(Y, rowbuf, b0 + 16);
        load16(tp, tps + 0);   fma16(f, tp, X, Y);
        load16s(Z, rowbuf, b0 - 16);
        load16(tp, tps + 16);  fma16(f, tp, Z, X);
        load16s(Y, rowbuf, b0 - 32);
        load16(tp, tps + 32);  fma16(f, tp, Y, Z);
        load16s(X, rowbuf, b0 - 48);
        load16(tp, tps + 48);  fma16(f, tp, X, Y);
    }

    // ---- Phase C2: tail taps 64..127 (delays 192..255) -> only outputs t>=192.
    //      Dense assignment: lane l16 computes partials for t' = 192+4*l16+{0..3}.
    float g[4] = {0.f, 0.f, 0.f, 0.f};
#pragma unroll
    for (int c = 0; c < 4; ++c) {
        float W[20];
#pragma unroll
        for (int x = 0; x < 5; ++x) {
            float4 v = *(const float4*)(rowbuf + PHYS(48 + 4 * l16 - 16 * c + 4 * x));
            W[4*x] = v.x; W[4*x+1] = v.y; W[4*x+2] = v.z; W[4*x+3] = v.w;
        }
        float tp2[16];
        load16(tp2, tps + 64 + 16 * c);
#pragma unroll
        for (int kk = 0; kk < 16; ++kk) {
            float t = tp2[kk];
#pragma unroll
            for (int d = 0; d < 4; ++d)
                g[d] = fmaf(t, W[16 + d - kk], g[d]);   // index in [1,19]
        }
    }
    // exchange partials via row scratch (overwrites taps[64..128) — all reads done;
    // same-wave DS ops are in-order, no barrier needed)
    *(float4*)(tps + 64 + 4 * l16) = make_float4(g[0], g[1], g[2], g[3]);
    if (l16 >= 12) {
        const float* sc = tps + 64 + ((l16 - 12) << 4);
#pragma unroll
        for (int x = 0; x < 4; ++x) {
            float4 v = *(const float4*)(sc + 4 * x);
            f[4*x]   += v.x; f[4*x+1] += v.y;
            f[4*x+2] += v.z; f[4*x+3] += v.w;
        }
    }

    // ---- store ----
    float* op = out + (row0 + r) * HOPS + t0;
#pragma unroll
    for (int x = 0; x < 4; ++x)
        *(float4*)(op + 4 * x) = make_float4(f[4*x], f[4*x+1], f[4*x+2], f[4*x+3]);
}

extern "C" void kernel_launch(void* const* d_in, const int* in_sizes, int n_in,
                              void* d_out, int out_size, void* d_ws, size_t ws_size,
                              hipStream_t stream) {
    const float* fb = (const float*)d_in[0];
    const float* nz = (const float*)d_in[1];
    float* o = (float*)d_out;
    const int rows = 16 * 4096;              // 65536
    noisefilter_kernel<<<dim3(rows / RPB), dim3(THREADS), 0, stream>>>(fb, nz, o);
}

// Round 3
// 147.061 us; speedup vs baseline: 1.0450x; 1.0450x over previous
//
#include <hip/hip_runtime.h>
#include <math.h>

#define NB 65
#define HOPS 256
#define RPB 8           // rows per block
#define THREADS 128     // 16 lanes per row; 2 waves/block, each wave owns 4 rows
#define TAPS_OFF 320    // noise/zero region is [0,320) with XOR swizzle (no pads)
#define RSTRIDE 460     // 320 + 128 taps + 12 pad (460%32==12 rotates rows by 3 slots)

// XOR swizzle at float4-slot granularity within each 32-float line:
// i = 32L + 4u + b  ->  32L + 4*(u ^ (L&7)) + b.
// C1 reads (lane stride 16 floats) and C2 reads (lane stride 4 floats) both
// become 2-way max (free); float4 contiguity/alignment preserved.
#define PHYS(i) ( ((i) & ~31) | (((((i) >> 2) ^ ((i) >> 5)) & 7) << 2) | ((i) & 3) )

// Zero-cost phase fence: all LDS traffic is intra-wave (DS pipe is in-order per
// wave), so we only need to stop the COMPILER from moving memory ops across.
#define WAVE_FENCE() do { asm volatile("" ::: "memory"); __builtin_amdgcn_wave_barrier(); } while (0)

__device__ __forceinline__ void load16(float (&d)[16], const float* p) {
#pragma unroll
    for (int x = 0; x < 4; ++x) {
        float4 v = *(const float4*)(p + 4 * x);
        d[4*x] = v.x; d[4*x+1] = v.y; d[4*x+2] = v.z; d[4*x+3] = v.w;
    }
}
__device__ __forceinline__ void load16s(float (&d)[16], const float* rowbuf, int L) {
#pragma unroll
    for (int x = 0; x < 4; ++x) {
        float4 v = *(const float4*)(rowbuf + PHYS(L + 4 * x));
        d[4*x] = v.x; d[4*x+1] = v.y; d[4*x+2] = v.z; d[4*x+3] = v.w;
    }
}
// window w[j] = j<16 ? lo[j] : hi[j-16], j = 16+d-kk in [1,31]
__device__ __forceinline__ void fma16(float (&f)[16], const float (&tp)[16],
                                      const float (&lo)[16], const float (&hi)[16]) {
#pragma unroll
    for (int kk = 0; kk < 16; ++kk) {
        float t = tp[kk];
#pragma unroll
        for (int d = 0; d < 16; ++d) {
            int j = 16 + d - kk;
            f[d] = fmaf(t, (j < 16) ? lo[j] : hi[j - 16], f[d]);
        }
    }
}

__global__ __launch_bounds__(THREADS, 4) void noisefilter_kernel(
    const float* __restrict__ fb,   // [65536][65]
    const float* __restrict__ nz,   // [65536][256]
    float* __restrict__ out)        // [65536][256]
{
    __shared__ float lds[RPB * RSTRIDE];
    const int tid  = threadIdx.x;
    const int wv   = tid >> 6;       // wave within block (0,1); wave owns rows 4wv..4wv+3
    const int lane = tid & 63;
    const int r    = tid >> 4;       // row within block (0..7)
    const int l16  = tid & 15;       // lane within row group
    const int t0   = l16 << 4;       // first output index of this thread
    const size_t row0 = (size_t)blockIdx.x * RPB;
    float* rowbuf = &lds[r * RSTRIDE];

    // ---- stage amp (65 floats/row) — each wave stages ITS OWN 4 rows ----
    {
        const float* fbw = fb + (row0 + 4 * wv) * NB;
        float* base = &lds[(4 * wv) * RSTRIDE];
        for (int i = lane; i < 4 * NB; i += 64) {
            int rr = i / NB;
            int k  = i - rr * NB;
            base[rr * RSTRIDE + TAPS_OFF + k] = fbw[i];
        }
    }

    // ---- prefetch noise for own wave's 4 rows (consumed after Goertzel) ----
    const float4* nz4 = (const float4*)(nz + (row0 + 4 * wv) * HOPS);
    float4 nv[4];
#pragma unroll
    for (int p = 0; p < 4; ++p) nv[p] = nz4[lane + p * 64];

    WAVE_FENCE();   // amp ds_writes above, Goertzel ds_reads below (intra-wave, in-order)

    // ---- Phase A: even/odd-split Goertzel; lane gets (nA,64-nA),(nB,64-nB), n=32 shared.
    const float alphaA = (float)l16 * 0.04908738521234052f;          // pi/64 * nA
    const float alphaB = alphaA + 0.7853981633974483f;               // + pi/4
    const float cA = __cosf(alphaA), cB = __cosf(alphaB);
    const float c2A = fmaf(2.0f * cA, cA, -1.0f);                    // cos(2a)
    const float c2B = fmaf(2.0f * cB, cB, -1.0f);
    const float k2A = c2A + c2A, k2B = c2B + c2B;

    float eA1=0.f,eA2=0.f,oA1=0.f,oA2=0.f;
    float eB1=0.f,eB2=0.f,oB1=0.f,oB2=0.f;
    float s32 = 0.f, a0r = 0.f, a64r;

    const float* amp = rowbuf + TAPS_OFF;
    {   // k = 64 (even chain m=32; n=32 sign +)
        float a = amp[64];
        a64r = a;
        { float t = a - eA2; float s = fmaf(k2A, eA1, t); eA2 = eA1; eA1 = s; }
        { float t = a - eB2; float s = fmaf(k2B, eB1, t); eB2 = eB1; eB1 = s; }
        s32 += a;
    }
#pragma unroll
    for (int kb = 48; kb >= 0; kb -= 16) {
        float ab[16];
        load16(ab, amp + kb);
#pragma unroll
        for (int kk = 15; kk >= 0; --kk) {
            float a = ab[kk];
            if (kk & 1) {   // odd k
                { float t = a - oA2; float s = fmaf(k2A, oA1, t); oA2 = oA1; oA1 = s; }
                { float t = a - oB2; float s = fmaf(k2B, oB1, t); oB2 = oB1; oB1 = s; }
            } else {        // even k
                { float t = a - eA2; float s = fmaf(k2A, eA1, t); eA2 = eA1; eA1 = s; }
                { float t = a - eB2; float s = fmaf(k2B, eB1, t); eB2 = eB1; eB1 = s; }
                if ((kk >> 1) & 1) s32 -= a; else s32 += a;
            }
        }
        if (kb == 0) a0r = ab[0];
    }

    const float EA = fmaf(-c2A, eA2, eA1);
    const float OA = cA * (oA1 - oA2);
    const float EB = fmaf(-c2B, eB2, eB1);
    const float OB = cB * (oB1 - oB2);
    const float pm = (l16 & 1) ? -1.f : 1.f;      // (-1)^n
    const float corr = fmaf(pm, a64r, a0r);
    const float inv = 1.0f / 256.0f;
    float* tps = rowbuf + TAPS_OFF;

    {   // pair A: n = l16, mirror 64-l16
        float GA  = fmaf(2.f, EA + OA, -corr);
        float GAm = fmaf(2.f, EA - OA, -corr);
        float TA  = GA  * (1.0f + cA) * inv;
        float TAm = GAm * (1.0f - cA) * inv;
        tps[l16] = TA;
        tps[64 - l16] = TAm;
        if (l16 >= 1) { tps[128 - l16] = TA; tps[64 + l16] = TAm; }
    }
    {   // pair B: n = 16+l16, mirror 48-l16
        float GB  = fmaf(2.f, EB + OB, -corr);
        float GBm = fmaf(2.f, EB - OB, -corr);
        float TB  = GB  * (1.0f + cB) * inv;
        float TBm = GBm * (1.0f - cB) * inv;
        tps[16 + l16] = TB;  tps[112 - l16] = TB;
        tps[48 - l16] = TBm; tps[80 + l16]  = TBm;
    }
    if (l16 == 0) {   // n = 32 (single lane: avoid 16-way same-address write)
        float G32 = fmaf(2.f, s32, -(a0r + a64r));
        float T32 = G32 * inv;
        tps[32] = T32;
        tps[96] = T32;
    }

    // ---- zero logical [0,64) of own row (one float4 per lane) ----
    *(float4*)(rowbuf + PHYS(4 * l16)) = make_float4(0.f, 0.f, 0.f, 0.f);

    // ---- store noise (2u-1) into logical [64,320) of own wave's rows ----
#pragma unroll
    for (int p = 0; p < 4; ++p) {
        float4 v = nv[p];
        int o  = (lane << 2) + 64;          // row 4wv+p, offset 4*lane+64
        *(float4*)(&lds[(4 * wv + p) * RSTRIDE + PHYS(o)]) =
            make_float4(fmaf(2.f, v.x, -1.f), fmaf(2.f, v.y, -1.f),
                        fmaf(2.f, v.z, -1.f), fmaf(2.f, v.w, -1.f));
    }

    WAVE_FENCE();   // tap/zero/noise ds_writes above, C1/C2 ds_reads below (intra-wave)

    // ---- Phase C1: taps 0..63 (delays 0..63), all 256 outputs, sliding window ----
    float f[16];
#pragma unroll
    for (int d = 0; d < 16; ++d) f[d] = 0.f;
    float X[16], Y[16], Z[16], tp[16];
    {
        const int b0 = t0 + 48;
        load16s(X, rowbuf, b0);      load16s(Y, rowbuf, b0 + 16);
        load16(tp, tps + 0);   fma16(f, tp, X, Y);
        load16s(Z, rowbuf, b0 - 16);
        load16(tp, tps + 16);  fma16(f, tp, Z, X);
        load16s(Y, rowbuf, b0 - 32);
        load16(tp, tps + 32);  fma16(f, tp, Y, Z);
        load16s(X, rowbuf, b0 - 48);
        load16(tp, tps + 48);  fma16(f, tp, X, Y);
    }

    // ---- Phase C2: tail taps 64..127 (delays 192..255) -> only outputs t>=192.
    //      Dense assignment: lane l16 computes partials for t' = 192+4*l16+{0..3}.
    float g[4] = {0.f, 0.f, 0.f, 0.f};
#pragma unroll
    for (int c = 0; c < 4; ++c) {
        float W[20];
#pragma unroll
        for (int x = 0; x < 5; ++x) {
            float4 v = *(const float4*)(rowbuf + PHYS(48 + 4 * l16 - 16 * c + 4 * x));
            W[4*x] = v.x; W[4*x+1] = v.y; W[4*x+2] = v.z; W[4*x+3] = v.w;
        }
        float tp2[16];
        load16(tp2, tps + 64 + 16 * c);
#pragma unroll
        for (int kk = 0; kk < 16; ++kk) {
            float t = tp2[kk];
#pragma unroll
            for (int d = 0; d < 4; ++d)
                g[d] = fmaf(t, W[16 + d - kk], g[d]);   // index in [1,19]
        }
    }
    // exchange partials via row scratch (overwrites taps[64..128) — all reads done;
    // same-wave DS ops are in-order, no barrier needed)
    *(float4*)(tps + 64 + 4 * l16) = make_float4(g[0], g[1], g[2], g[3]);
    if (l16 >= 12) {
        const float* sc = tps + 64 + ((l16 - 12) << 4);
#pragma unroll
        for (int x = 0; x < 4; ++x) {
            float4 v = *(const float4*)(sc + 4 * x);
            f[4*x]   += v.x; f[4*x+1] += v.y;
            f[4*x+2] += v.z; f[4*x+3] += v.w;
        }
    }

    // ---- store ----
    float* op = out + (row0 + r) * HOPS + t0;
#pragma unroll
    for (int x = 0; x < 4; ++x)
        *(float4*)(op + 4 * x) = make_float4(f[4*x], f[4*x+1], f[4*x+2], f[4*x+3]);
}

extern "C" void kernel_launch(void* const* d_in, const int* in_sizes, int n_in,
                              void* d_out, int out_size, void* d_ws, size_t ws_size,
                              hipStream_t stream) {
    const float* fb = (const float*)d_in[0];
    const float* nz = (const float*)d_in[1];
    float* o = (float*)d_out;
    const int rows = 16 * 4096;              // 65536
    noisefilter_kernel<<<dim3(rows / RPB), dim3(THREADS), 0, stream>>>(fb, nz, o);
}